// Round 5
// baseline (419.107 us; speedup 1.0000x reference)
//
#include <hip/hip_runtime.h>
#include <stdint.h>

typedef unsigned short u16b;
typedef short s16x4 __attribute__((ext_vector_type(4)));
typedef short s16x8 __attribute__((ext_vector_type(8)));
typedef float f32x4 __attribute__((ext_vector_type(4)));

__device__ __forceinline__ u16b f2bf(float f) {
    uint32_t u = __float_as_uint(f);
    uint32_t r = (u + 0x7FFFu + ((u >> 16) & 1u)) >> 16;
    return (u16b)r;
}
__device__ __forceinline__ u16b f2bf_fast(float f) {
    return (u16b)((__float_as_uint(f) + 0x8000u) >> 16);
}
__device__ __forceinline__ float bf2f(u16b h) {
    return __uint_as_float(((uint32_t)h) << 16);
}

typedef const __attribute__((address_space(1))) void* gas_ptr;
typedef __attribute__((address_space(3))) void* las_ptr;
__device__ __forceinline__ void gload_lds16(const void* g, void* l) {
    __builtin_amdgcn_global_load_lds((gas_ptr)g, (las_ptr)l, 16, 0, 0);
}

__device__ __forceinline__ f32x4 mfma16_bf16(s16x4 a, s16x4 b, f32x4 c) {
#if __has_builtin(__builtin_amdgcn_mfma_f32_16x16x16_bf16)
    return __builtin_amdgcn_mfma_f32_16x16x16_bf16(a, b, c, 0, 0, 0);
#elif __has_builtin(__builtin_amdgcn_mfma_f32_16x16x16bf16_1k)
    return __builtin_amdgcn_mfma_f32_16x16x16bf16_1k(a, b, c, 0, 0, 0);
#else
    f32x4 d;
    asm("v_mfma_f32_16x16x16_bf16 %0, %1, %2, %3" : "=v"(d) : "v"(a), "v"(b), "v"(c));
    return d;
#endif
}

// ---------------- weight cast: original bf16, lo-permuted bf16, proj bf16 ----------------
// W2[n][pp*128 + chan'] = W[n][chan'*4 + pp]  (pp = ii*2+jj pixel part of the unfold index)
__global__ void cast_weights(const float* __restrict__ wqkv, const float* __restrict__ wproj,
                             u16b* __restrict__ wqkv_bf, u16b* __restrict__ wqkv_perm,
                             u16b* __restrict__ wproj_bf) {
    int i = blockIdx.x * 256 + threadIdx.x;
    if (i < 1536 * 512) {
        wqkv_bf[i] = f2bf(wqkv[i]);
        int n = i >> 9, kp = i & 511;
        int pp = kp >> 7, chp = kp & 127;
        wqkv_perm[i] = f2bf(wqkv[n * 512 + chp * 4 + pp]);
    }
    if (i < 512 * 512) wproj_bf[i] = f2bf(wproj[i]);
}

// ---------------- 2x2 avg pool: x[B,64,64,C] -> x_hi[B,32*32,C] bf16 ----------------
__global__ void pool_kernel(const float* __restrict__ x, u16b* __restrict__ x_hi) {
    int i = blockIdx.x * 256 + threadIdx.x;      // 8*1024*512
    int c = i & 511;
    int t = i >> 9;
    int wj = t & 31, wi = (t >> 5) & 31, b = t >> 10;
    const float* p = x + ((size_t)b * 4096 + (size_t)(wi * 2) * 64 + wj * 2) * 512 + c;
    float s = p[0] + p[512] + p[64 * 512] + p[65 * 512];
    x_hi[i] = f2bf(s * 0.25f);
}

// ---------------- m97-style GEMM with XOR-swizzled LDS (hi qkv + final proj) ----------------
template <int OUT_F32>
__global__ __launch_bounds__(256) void gemm_bt(const u16b* __restrict__ A, const u16b* __restrict__ Bt,
                                               u16b* __restrict__ Cbf, float* __restrict__ Cf,
                                               const float* __restrict__ bias, int M, int Nn, int K) {
    __shared__ u16b As[128 * 64];
    __shared__ u16b Bs[128 * 64];
    int tid = threadIdx.x;
    int wave = tid >> 6, lane = tid & 63;
    int quad = lane >> 4, l15 = lane & 15;
    int m0 = blockIdx.y * 128, n0 = blockIdx.x * 128;
    int wm = (wave >> 1) * 64, wn = (wave & 1) * 64;

    f32x4 acc[4][4] = {};

    int ldrow = lane >> 3;
    int ldk = ((lane & 7) ^ ldrow) * 8;
    int fsw0 = (quad ^ (l15 & 7)) * 8;
    int fsw1 = ((4 + quad) ^ (l15 & 7)) * 8;

    for (int kc = 0; kc < K; kc += 64) {
#pragma unroll
        for (int i = 0; i < 4; ++i) {
            int chunk = wave * 4 + i;
            int row = chunk * 8 + ldrow;
            gload_lds16(A + (size_t)(m0 + row) * K + kc + ldk, As + chunk * 512);
            gload_lds16(Bt + (size_t)(n0 + row) * K + kc + ldk, Bs + chunk * 512);
        }
        __syncthreads();
#pragma unroll
        for (int ks = 0; ks < 2; ++ks) {
            int fo = ks ? fsw1 : fsw0;
            s16x8 a[4], b[4];
#pragma unroll
            for (int mi = 0; mi < 4; ++mi)
                a[mi] = *(const s16x8*)(As + (wm + mi * 16 + l15) * 64 + fo);
#pragma unroll
            for (int ni = 0; ni < 4; ++ni)
                b[ni] = *(const s16x8*)(Bs + (wn + ni * 16 + l15) * 64 + fo);
#pragma unroll
            for (int mi = 0; mi < 4; ++mi)
#pragma unroll
                for (int ni = 0; ni < 4; ++ni)
                    acc[mi][ni] = __builtin_amdgcn_mfma_f32_16x16x32_bf16(a[mi], b[ni], acc[mi][ni], 0, 0, 0);
        }
        __syncthreads();
    }

#pragma unroll
    for (int mi = 0; mi < 4; ++mi)
#pragma unroll
        for (int ni = 0; ni < 4; ++ni) {
            int row = m0 + wm + mi * 16 + quad * 4;
            int col = n0 + wn + ni * 16 + l15;
            if (OUT_F32) {
                float bv = bias[col];
#pragma unroll
                for (int r = 0; r < 4; ++r)
                    Cf[(size_t)(row + r) * Nn + col] = acc[mi][ni][r] + bv;
            } else {
#pragma unroll
                for (int r = 0; r < 4; ++r)
                    Cbf[(size_t)(row + r) * Nn + col] = f2bf(acc[mi][ni][r]);
            }
        }
}

// ---------------- lo-branch qkv GEMM with fused window-pack (reads x directly) ----------------
// A[token=(w,t)][k'=pp*128+chan'] = x[pix(w,pp)][t*128+chan'] (f32 -> bf16 in VGPRs),
// B = wqkv_perm via global_load_lds. M=32768, N=1536, K=512.
__global__ __launch_bounds__(256) void gemm_lo_fused(const float* __restrict__ x,
                                                     const u16b* __restrict__ W2,
                                                     u16b* __restrict__ qkv_lo) {
    __shared__ u16b As[128 * 64];
    __shared__ u16b Bs[128 * 64];
    int tid = threadIdx.x;
    int wave = tid >> 6, lane = tid & 63;
    int quad = lane >> 4, l15 = lane & 15;
    int n0 = blockIdx.x * 128, m0 = blockIdx.y * 128;
    int wm = (wave >> 1) * 64, wn = (wave & 1) * 64;

    f32x4 acc[4][4] = {};

    int ldrow = lane >> 3;
    int ldk = ((lane & 7) ^ ldrow) * 8;
    int fsw0 = (quad ^ (l15 & 7)) * 8;
    int fsw1 = ((4 + quad) ^ (l15 & 7)) * 8;

    // A staging geometry: lane covers row arow, column half ahalf (32 of 64)
    int arow = wave * 32 + (lane >> 1);          // 0..127
    int ahalf = lane & 1;
    int token = m0 + arow;
    int bb = token >> 12, tok = token & 4095;
    int w = tok >> 2, t = tok & 3;
    int wi = w >> 5, wj = w & 31;
    const float* xrow[4];
#pragma unroll
    for (int pp = 0; pp < 4; ++pp)
        xrow[pp] = x + ((size_t)(bb * 4096 + (wi * 2 + (pp >> 1)) * 64 + wj * 2 + (pp & 1))) * 512
                     + t * 128 + ahalf * 32;

    for (int kc = 0; kc < 512; kc += 64) {
        int pp = kc >> 7, ch0 = kc & 64;
        const float* src = xrow[pp] + ch0;
#pragma unroll
        for (int i = 0; i < 4; ++i) {
            f32x4 u = *(const f32x4*)(src + i * 8);
            f32x4 v = *(const f32x4*)(src + i * 8 + 4);
            s16x8 pk;
#pragma unroll
            for (int j = 0; j < 4; ++j) pk[j] = (short)f2bf_fast(u[j]);
#pragma unroll
            for (int j = 0; j < 4; ++j) pk[4 + j] = (short)f2bf_fast(v[j]);
            int slice = ahalf * 4 + i;
            *(s16x8*)&As[arow * 64 + (slice ^ (arow & 7)) * 8] = pk;
        }
#pragma unroll
        for (int i = 0; i < 4; ++i) {
            int chunk = wave * 4 + i;
            int row = chunk * 8 + ldrow;
            gload_lds16(W2 + (size_t)(n0 + row) * 512 + kc + ldk, Bs + chunk * 512);
        }
        __syncthreads();
#pragma unroll
        for (int ks = 0; ks < 2; ++ks) {
            int fo = ks ? fsw1 : fsw0;
            s16x8 a[4], b[4];
#pragma unroll
            for (int mi = 0; mi < 4; ++mi)
                a[mi] = *(const s16x8*)(As + (wm + mi * 16 + l15) * 64 + fo);
#pragma unroll
            for (int ni = 0; ni < 4; ++ni)
                b[ni] = *(const s16x8*)(Bs + (wn + ni * 16 + l15) * 64 + fo);
#pragma unroll
            for (int mi = 0; mi < 4; ++mi)
#pragma unroll
                for (int ni = 0; ni < 4; ++ni)
                    acc[mi][ni] = __builtin_amdgcn_mfma_f32_16x16x32_bf16(a[mi], b[ni], acc[mi][ni], 0, 0, 0);
        }
        __syncthreads();
    }

#pragma unroll
    for (int mi = 0; mi < 4; ++mi)
#pragma unroll
        for (int ni = 0; ni < 4; ++ni) {
            int row = m0 + wm + mi * 16 + quad * 4;
            int col = n0 + wn + ni * 16 + l15;
#pragma unroll
            for (int r = 0; r < 4; ++r)
                qkv_lo[(size_t)(row + r) * 1536 + col] = f2bf(acc[mi][ni][r]);
        }
}

// ---------------- V transpose for hi branch: vt[bh, d, n] ----------------
__global__ __launch_bounds__(256) void transpose_v(const u16b* __restrict__ qkv, u16b* __restrict__ vt) {
    __shared__ u16b tile[64 * 72];
    int bh = blockIdx.y, nt = blockIdx.x;
    int b = bh >> 3, h = bh & 7;
    int tid = threadIdx.x;
    int row = tid >> 2, part = tid & 3;
    const u16b* src = qkv + ((size_t)b * 1024 + nt * 64 + row) * 1536 + 1024 + h * 64 + part * 16;
    *(s16x8*)&tile[row * 72 + part * 16] = *(const s16x8*)src;
    *(s16x8*)&tile[row * 72 + part * 16 + 8] = *(const s16x8*)(src + 8);
    __syncthreads();
    u16b* dst = vt + ((size_t)bh * 64 + row) * 1024 + nt * 64 + part * 16;
#pragma unroll
    for (int j = 0; j < 16; ++j) dst[j] = tile[(part * 16 + j) * 72 + row];
}

// ---------------- hi-branch attention (round-4 version, unchanged) ----------------
__global__ __launch_bounds__(256) void attn_hi(const u16b* __restrict__ qkv,
                                               const u16b* __restrict__ vt,
                                               u16b* __restrict__ out_hi) {
    __shared__ u16b Ks[2][64 * 64];
    __shared__ u16b Vs[2][64 * 64];
    __shared__ u16b P[4][16 * 64];
    int tid = threadIdx.x, wave = tid >> 6, lane = tid & 63;
    int quad = lane >> 4, l15 = lane & 15;
    int bh = blockIdx.x;
    int qb = blockIdx.y;
    int b = bh >> 3, h = bh & 7;
    int qr0 = qb * 64 + wave * 16;

    const size_t qkv_b = (size_t)b * 1024 * 1536;
    const u16b* kg = qkv + qkv_b + 512 + h * 64;
    const u16b* vg = vt + (size_t)bh * 64 * 1024;

    int srow8 = lane >> 3;
    int ssw = ((lane & 7) ^ srow8) * 8;
    int fsw0 = (quad ^ (l15 & 7)) * 8;
    int fsw1 = ((4 + quad) ^ (l15 & 7)) * 8;

    s16x8 qf[2];
    qf[0] = *(const s16x8*)(qkv + qkv_b + (size_t)(qr0 + l15) * 1536 + h * 64 + quad * 8);
    qf[1] = *(const s16x8*)(qkv + qkv_b + (size_t)(qr0 + l15) * 1536 + h * 64 + 32 + quad * 8);

#pragma unroll
    for (int i = 0; i < 2; ++i) {
        int chunk = wave * 2 + i;
        int row = chunk * 8 + srow8;
        gload_lds16(kg + (size_t)row * 1536 + ssw, (u16b*)Ks[0] + chunk * 512);
        gload_lds16(vg + (size_t)row * 1024 + ssw, (u16b*)Vs[0] + chunk * 512);
    }

    f32x4 o[4] = {};
    f32x4 ls = {0.f, 0.f, 0.f, 0.f};
    u16b* pl = P[wave];
    const float c_scale = 0.18033688011f;

    for (int kb = 0; kb < 16; ++kb) {
        int cur = kb & 1, nxt = cur ^ 1;
        __syncthreads();
        if (kb < 15) {
#pragma unroll
            for (int i = 0; i < 2; ++i) {
                int chunk = wave * 2 + i;
                int row = chunk * 8 + srow8;
                gload_lds16(kg + (size_t)((kb + 1) * 64 + row) * 1536 + ssw, (u16b*)Ks[nxt] + chunk * 512);
                gload_lds16(vg + (size_t)row * 1024 + (kb + 1) * 64 + ssw, (u16b*)Vs[nxt] + chunk * 512);
            }
        }
        const u16b* Kc = Ks[cur];
        const u16b* Vc = Vs[cur];

        f32x4 s[4] = {};
#pragma unroll
        for (int nt = 0; nt < 4; ++nt) {
            s16x8 kf0 = *(const s16x8*)(Kc + (nt * 16 + l15) * 64 + fsw0);
            s16x8 kf1 = *(const s16x8*)(Kc + (nt * 16 + l15) * 64 + fsw1);
            s[nt] = __builtin_amdgcn_mfma_f32_16x16x32_bf16(qf[0], kf0, s[nt], 0, 0, 0);
            s[nt] = __builtin_amdgcn_mfma_f32_16x16x32_bf16(qf[1], kf1, s[nt], 0, 0, 0);
        }
#pragma unroll
        for (int nt = 0; nt < 4; ++nt) {
            f32x4 p;
#pragma unroll
            for (int r = 0; r < 4; ++r) p[r] = exp2f(s[nt][r] * c_scale);
            ls += p;
#pragma unroll
            for (int r = 0; r < 4; ++r) {
                int prow = quad * 4 + r;
                int slc = (nt * 2 + (l15 >> 3)) ^ (prow & 7);
                pl[prow * 64 + slc * 8 + (l15 & 7)] = f2bf_fast(p[r]);
            }
        }
        s16x8 pa0 = *(const s16x8*)(pl + l15 * 64 + fsw0);
        s16x8 pa1 = *(const s16x8*)(pl + l15 * 64 + fsw1);
#pragma unroll
        for (int nd = 0; nd < 4; ++nd) {
            s16x8 vf0 = *(const s16x8*)(Vc + (nd * 16 + l15) * 64 + fsw0);
            s16x8 vf1 = *(const s16x8*)(Vc + (nd * 16 + l15) * 64 + fsw1);
            o[nd] = __builtin_amdgcn_mfma_f32_16x16x32_bf16(pa0, vf0, o[nd], 0, 0, 0);
            o[nd] = __builtin_amdgcn_mfma_f32_16x16x32_bf16(pa1, vf1, o[nd], 0, 0, 0);
        }
    }

    float rs[4];
#pragma unroll
    for (int r = 0; r < 4; ++r) {
        float t = ls[r];
#pragma unroll
        for (int msk = 1; msk < 16; msk <<= 1) t += __shfl_xor(t, msk);
        rs[r] = 1.f / t;
    }
#pragma unroll
    for (int nd = 0; nd < 4; ++nd)
#pragma unroll
        for (int r = 0; r < 4; ++r) {
            int row = qr0 + quad * 4 + r;
            int col = h * 64 + nd * 16 + l15;
            out_hi[((size_t)b * 1024 + row) * 512 + col] = f2bf(o[nd][r] * rs[r]);
        }
}

// ---------------- lo-branch attention via chained MFMA + fused upsample-add ----------------
// One wave = 4 windows x 1 head. S^T = mfma32(A=K,B=Q): C-layout lane(quad,l15) reg r holds
// S[query=l15][key=quad*4+r]. After exp/mask/normalize, that register IS the A-operand of
// mfma_16x16x16 (m=l15, k=quad*4+r) for PV -- no LDS, no shuffles except 2 for rowsum.
__global__ __launch_bounds__(256) void attn_lo_up(const u16b* __restrict__ qkv_lo,  // [B,1024,4,1536]
                                                  const u16b* __restrict__ out_hi,  // [B,1024,512]
                                                  u16b* __restrict__ attn_sum) {    // [B,4096,512]
    int tid = threadIdx.x, wave = tid >> 6, lane = tid & 63;
    int quad = lane >> 4, l15 = lane & 15;
    int wg = blockIdx.x * 4 + wave;            // 0..16383
    int wgroup = wg & 255, h = (wg >> 8) & 7, b = wg >> 11;
    const float c_scale = 0.18033688011f;      // 0.125 * log2(e)

    // Q/K fragments: lane's token = (window wgroup*4 + l15>>2, t = l15&3)
    const u16b* qp = qkv_lo + ((size_t)((b * 1024 + wgroup * 4 + (l15 >> 2)) * 4 + (l15 & 3))) * 1536 + h * 64;
    s16x8 qf0 = *(const s16x8*)(qp + quad * 8);
    s16x8 qf1 = *(const s16x8*)(qp + 32 + quad * 8);
    s16x8 kf0 = *(const s16x8*)(qp + 512 + quad * 8);
    s16x8 kf1 = *(const s16x8*)(qp + 512 + 32 + quad * 8);

    f32x4 st = {0.f, 0.f, 0.f, 0.f};
    st = __builtin_amdgcn_mfma_f32_16x16x32_bf16(kf0, qf0, st, 0, 0, 0);
    st = __builtin_amdgcn_mfma_f32_16x16x32_bf16(kf1, qf1, st, 0, 0, 0);

    // block-diagonal mask: key window (=quad) must equal query window (=l15>>2)
    bool valid = (quad == (l15 >> 2));
    float p[4], rs = 0.f;
#pragma unroll
    for (int r = 0; r < 4; ++r) {
        float e = valid ? exp2f(st[r] * c_scale) : 0.f;
        p[r] = e; rs += e;
    }
    rs += __shfl_xor(rs, 16);
    rs += __shfl_xor(rs, 32);                  // rowsum for query l15, broadcast to all quads
    float pinv = 1.f / rs;
    s16x4 pa;
#pragma unroll
    for (int r = 0; r < 4; ++r) pa[r] = (short)f2bf_fast(p[r] * pinv);

    // PV: B[k=quad*4+j][n=l15] = V[window quad, token j][channel chunk*16+l15]
    const u16b* vbase = qkv_lo + ((size_t)((b * 1024 + wgroup * 4 + quad) * 4)) * 1536 + 1024 + h * 64 + l15;
    f32x4 o[4];
#pragma unroll
    for (int ch = 0; ch < 4; ++ch) {
        s16x4 vb;
#pragma unroll
        for (int j = 0; j < 4; ++j) vb[j] = (short)vbase[(size_t)j * 1536 + ch * 16];
        f32x4 z = {0.f, 0.f, 0.f, 0.f};
        o[ch] = mfma16_bf16(pa, vb, z);
    }

    // output: lane(quad,l15) holds rows = query quad*4+r (window quad, tq=r), col = ch*16+l15
    int w_o = wgroup * 4 + quad;
    int wi = w_o >> 5, wj = w_o & 31;
    const u16b* hsrc = out_hi + ((size_t)b * 1024) * 512 + h * 64 + l15;
    u16b* dbase = attn_sum + ((size_t)b * 4096) * 512 + h * 64 + l15;
#pragma unroll
    for (int r = 0; r < 4; ++r) {
        int py = r >> 1, px = r & 1;
        int y0, y1, x0, x1;
        float wy0, wx0;
        if (py == 0) { y0 = wi > 0 ? wi - 1 : 0; y1 = wi; wy0 = 0.25f; }
        else         { y0 = wi; y1 = wi < 31 ? wi + 1 : 31; wy0 = 0.75f; }
        if (px == 0) { x0 = wj > 0 ? wj - 1 : 0; x1 = wj; wx0 = 0.25f; }
        else         { x0 = wj; x1 = wj < 31 ? wj + 1 : 31; wx0 = 0.75f; }
        float wy1 = 1.f - wy0, wx1 = 1.f - wx0;
        int p00 = (y0 * 32 + x0) * 512, p01 = (y0 * 32 + x1) * 512;
        int p10 = (y1 * 32 + x0) * 512, p11 = (y1 * 32 + x1) * 512;
        int pixn = (wi * 2 + py) * 64 + wj * 2 + px;
        u16b* dst = dbase + (size_t)pixn * 512;
#pragma unroll
        for (int ch = 0; ch < 4; ++ch) {
            int co = ch * 16;
            float vu = wy0 * (wx0 * bf2f(hsrc[p00 + co]) + wx1 * bf2f(hsrc[p01 + co]))
                     + wy1 * (wx0 * bf2f(hsrc[p10 + co]) + wx1 * bf2f(hsrc[p11 + co]));
            dst[co] = f2bf(o[ch][r] + vu);
        }
    }
}

// ---------------- launch ----------------
extern "C" void kernel_launch(void* const* d_in, const int* in_sizes, int n_in,
                              void* d_out, int out_size, void* d_ws, size_t ws_size,
                              hipStream_t stream) {
    (void)in_sizes; (void)n_in; (void)out_size; (void)ws_size;
    const float* x = (const float*)d_in[0];
    const float* Wqkv = (const float*)d_in[1];
    const float* Wproj = (const float*)d_in[2];
    const float* bproj = (const float*)d_in[3];
    float* out = (float*)d_out;

    char* ws = (char*)d_ws;
    size_t off = 0;
    auto alloc = [&](size_t bytes) { void* p = ws + off; off += bytes; return p; };
    u16b* wqkv_bf  = (u16b*)alloc((size_t)1536 * 512 * 2);
    u16b* wqkv_perm= (u16b*)alloc((size_t)1536 * 512 * 2);
    u16b* wproj_bf = (u16b*)alloc((size_t)512 * 512 * 2);
    u16b* x_hi     = (u16b*)alloc((size_t)8 * 1024 * 512 * 2);
    u16b* qkv_hi   = (u16b*)alloc((size_t)8 * 1024 * 1536 * 2);
    u16b* qkv_lo   = (u16b*)alloc((size_t)8 * 4096 * 1536 * 2);
    u16b* vt       = (u16b*)alloc((size_t)64 * 64 * 1024 * 2);
    u16b* out_hi   = (u16b*)alloc((size_t)8 * 1024 * 512 * 2);
    u16b* attn_sum = (u16b*)alloc((size_t)8 * 4096 * 512 * 2);

    cast_weights<<<dim3(3072), dim3(256), 0, stream>>>(Wqkv, Wproj, wqkv_bf, wqkv_perm, wproj_bf);
    pool_kernel<<<dim3(16384), dim3(256), 0, stream>>>(x, x_hi);
    gemm_bt<0><<<dim3(12, 64), dim3(256), 0, stream>>>(x_hi, wqkv_bf, qkv_hi, nullptr, nullptr, 8192, 1536, 512);
    gemm_lo_fused<<<dim3(12, 256), dim3(256), 0, stream>>>(x, wqkv_perm, qkv_lo);
    transpose_v<<<dim3(16, 64), dim3(256), 0, stream>>>(qkv_hi, vt);
    attn_hi<<<dim3(64, 16), dim3(256), 0, stream>>>(qkv_hi, vt, out_hi);
    attn_lo_up<<<dim3(4096), dim3(256), 0, stream>>>(qkv_lo, out_hi, attn_sum);
    gemm_bt<1><<<dim3(4, 256), dim3(256), 0, stream>>>(attn_sum, wproj_bf, nullptr, out, bproj, 32768, 512, 512);
}